// Round 3
// baseline (94.057 us; speedup 1.0000x reference)
//
#include <hip/hip_runtime.h>

// Conv2D per-batch 3x3x32 valid conv, int32 in, TFLite requant -> int8
// (harness stores integer outputs as int32). B=64, H_IN=W_IN=226, CIN=32,
// H_OUT=W_OUT=224.
//
// Layout: wave = 8 w-pairs (wi) x 8 channel-chunks (ci, 4 ints each).
// Each lane: 2 output columns, partial over 4 channels; 8-lane shfl reduce.
// 6-slot register sliding window over input rows, loads issued 2 rows ahead
// (~12-16 dwordx4 in flight per wave) to cover HBM latency.

typedef int int4v __attribute__((ext_vector_type(4)));
typedef int int2v __attribute__((ext_vector_type(2)));

#define B_       64
#define H_IN_    226
#define W_IN_    226
#define CIN_     32
#define H_OUT_   224
#define W_OUT_   224
#define ROWP     (W_IN_ * CIN_)      // 7232 ints per input row
#define IMGP     (H_IN_ * ROWP)      // ints per batch image
#define HB       56                  // output rows per wave (224 / 4 strips)

// Load one input row (4 consecutive w-positions of this lane's channel chunk).
// Max r used = 57 == last valid relative row (h0 max 168, 168+57 = 225) -> no clamp.
#define LOADROW(slot, r) {                                              \
    const int* p_ = base + (r) * ROWP;                                  \
    x[slot][0] = *(const int4v*)(p_);                                   \
    x[slot][1] = *(const int4v*)(p_ + CIN_);                            \
    x[slot][2] = *(const int4v*)(p_ + 2 * CIN_);                        \
    x[slot][3] = *(const int4v*)(p_ + 3 * CIN_);                        \
}

#define ACCUM(sm, m)                                                    \
    _Pragma("unroll")                                                   \
    for (int n = 0; n < 3; ++n) {                                       \
        _Pragma("unroll")                                               \
        for (int c = 0; c < 4; ++c) {                                   \
            a0 += __mul24(x[sm][n][c],     f[m][n][c]);                 \
            a1 += __mul24(x[sm][n + 1][c], f[m][n][c]);                 \
        }                                                               \
    }

#define BODY(s0, s1, s2, hh) {                                          \
    int a0 = 0, a1 = 0;                                                 \
    ACCUM(s0, 0) ACCUM(s1, 1) ACCUM(s2, 2)                              \
    a0 += __shfl_xor(a0, 1); a0 += __shfl_xor(a0, 2); a0 += __shfl_xor(a0, 4); \
    a1 += __shfl_xor(a1, 1); a1 += __shfl_xor(a1, 2); a1 += __shfl_xor(a1, 4); \
    if (ci == 0) {                                                      \
        long long v0 = (((long long)(a0 + bi)) * rm + rnd) >> ts;       \
        long long v1 = (((long long)(a1 + bi)) * rm + rnd) >> ts;       \
        int i0 = (int)v0 + zp, i1 = (int)v1 + zp;                       \
        i0 = min(127, max(-128, i0));                                   \
        i1 = min(127, max(-128, i1));                                   \
        int2v r_; r_[0] = i0; r_[1] = i1;                               \
        *reinterpret_cast<int2v*>(ob + (hh) * W_OUT_) = r_;             \
    }                                                                   \
}

__global__ __launch_bounds__(256) void conv2d_requant_kernel(
    const int* __restrict__ in,    // (64,226,226,32)
    const int* __restrict__ filt,  // (64,3,3,32)
    const int* __restrict__ bias,  // (64,)
    const int* __restrict__ qm_p,  // scalar
    const int* __restrict__ ex_p,  // scalar
    const int* __restrict__ zp_p,  // scalar
    int* __restrict__ out)         // (64,224,224,1) int8 values stored as int32
{
    const int bx   = blockIdx.x;           // 0..895
    const int b    = bx / 14;
    const int seg  = bx % 14;
    const int widx = seg * 4 + (threadIdx.x >> 6);  // 0..55 per batch
    const int strip = widx / 14;           // 0..3  -> h0 = strip*56
    const int wseg  = widx % 14;           // 0..13 -> w0 = wseg*16
    const int h0 = strip * HB;
    const int w0 = wseg * 16;
    const int lane = threadIdx.x & 63;
    const int wi = lane >> 3;              // 0..7 : pair of output columns
    const int ci = lane & 7;               // 0..7 : channel chunk (4 ints)

    // Requant constants (low dword of the scalar inputs is correct for values
    // fitting 32 bits, little-endian, whether stored as int32 or int64).
    const int qm = qm_p[0];
    const int ex = ex_p[0];
    const int zp = zp_p[0];
    const int rm = (qm < 2147418112) ? ((qm + (1 << 15)) >> 16) : 32767;
    const int ts = 15 - ex;
    const long long rnd = 1LL << (ts - 1);
    const int bi = bias[b];

    // Per-lane filter fragment: 3x3 x (4 channels of chunk ci)
    int f[3][3][4];
    {
        const int* fb = filt + b * 288 + ci * 4;
#pragma unroll
        for (int m = 0; m < 3; ++m) {
#pragma unroll
            for (int n = 0; n < 3; ++n) {
                int4v t = *(const int4v*)(fb + (m * 3 + n) * CIN_);
                f[m][n][0] = t[0]; f[m][n][1] = t[1];
                f[m][n][2] = t[2]; f[m][n][3] = t[3];
            }
        }
    }

    const int* base = in + b * IMGP + h0 * ROWP + (w0 + 2 * wi) * CIN_ + ci * 4;
    int* ob = out + (b * H_OUT_ + h0) * W_OUT_ + w0 + 2 * wi;

    // 6-slot sliding register window; loads run 2 rows ahead of compute.
    int4v x[6][4];
    LOADROW(0, 0)
    LOADROW(1, 1)
    LOADROW(2, 2)
    LOADROW(3, 3)

    for (int hh = 0; hh < 54; hh += 6) {
        LOADROW(4, hh + 4) LOADROW(5, hh + 5) BODY(0, 1, 2, hh)     BODY(1, 2, 3, hh + 1)
        LOADROW(0, hh + 6) LOADROW(1, hh + 7) BODY(2, 3, 4, hh + 2) BODY(3, 4, 5, hh + 3)
        LOADROW(2, hh + 8) LOADROW(3, hh + 9) BODY(4, 5, 0, hh + 4) BODY(5, 0, 1, hh + 5)
    }
    // Tail: rows 54, 55 (slots 0..3 hold rows 54..57)
    BODY(0, 1, 2, 54) BODY(1, 2, 3, 55)
}

extern "C" void kernel_launch(void* const* d_in, const int* in_sizes, int n_in,
                              void* d_out, int out_size, void* d_ws, size_t ws_size,
                              hipStream_t stream) {
    const int* in   = (const int*)d_in[0];
    const int* filt = (const int*)d_in[1];
    const int* bias = (const int*)d_in[2];
    const int* qm   = (const int*)d_in[3];
    const int* ex   = (const int*)d_in[4];
    const int* zp   = (const int*)d_in[5];
    int* out = (int*)d_out;

    dim3 grid(B_ * 14);   // 64 batches x 14 blocks (4 strips x 14 wsegs = 56 waves/batch)
    dim3 block(256);
    hipLaunchKernelGGL(conv2d_requant_kernel, grid, block, 0, stream,
                       in, filt, bias, qm, ex, zp, out);
}

// Round 4
// 88.419 us; speedup vs baseline: 1.0638x; 1.0638x over previous
//
#include <hip/hip_runtime.h>

// Conv2D per-batch 3x3x32 valid conv, int32 in (values are int8-range),
// TFLite requant -> int8 (harness stores integer outputs as int32).
// B=64, H_IN=W_IN=226, CIN=32, H_OUT=W_OUT=224.
//
// Key trick: inputs/filters are int8-range by construction, so pack 4
// channels/dword and MAC with v_dot4_i32_i8. Cuts the register window
// 64->16 VGPRs and filter 36->9 -> ~6-8 waves/SIMD for latency hiding.

typedef int int4v __attribute__((ext_vector_type(4)));
typedef int int2v __attribute__((ext_vector_type(2)));

#define B_       64
#define H_IN_    226
#define W_IN_    226
#define CIN_     32
#define H_OUT_   224
#define W_OUT_   224
#define ROWP     (W_IN_ * CIN_)      // 7232 ints per input row
#define IMGP     (H_IN_ * ROWP)
#define HB       28                  // output rows per wave
#define MAXREL   (HB + 1)            // last needed relative input row = 29

__device__ __forceinline__ int pack4(int a, int b, int c, int d) {
    return (a & 0xff) | ((b & 0xff) << 8) | ((c & 0xff) << 16) | (d << 24);
}

__device__ __forceinline__ int dot4(int a, int b, int c) {
#if __has_builtin(__builtin_amdgcn_sdot4)
    return __builtin_amdgcn_sdot4(a, b, c, false);
#else
    return c + ((a << 24) >> 24) * ((b << 24) >> 24)
             + ((a << 16) >> 24) * ((b << 16) >> 24)
             + ((a << 8)  >> 24) * ((b << 8)  >> 24)
             + ( a        >> 24) * ( b        >> 24);
#endif
}

// Load one input row (4 consecutive w of this lane's 4-channel chunk) into raw regs
#define LOADRAW(row) {                                                  \
    int rr_ = (row); if (rr_ > MAXREL) rr_ = MAXREL;                    \
    const int* p_ = base + rr_ * ROWP;                                  \
    r[0] = *(const int4v*)(p_);                                         \
    r[1] = *(const int4v*)(p_ + CIN_);                                  \
    r[2] = *(const int4v*)(p_ + 2 * CIN_);                              \
    r[3] = *(const int4v*)(p_ + 3 * CIN_);                              \
}

#define PACK(slot) {                                                    \
    P[slot][0] = pack4(r[0][0], r[0][1], r[0][2], r[0][3]);             \
    P[slot][1] = pack4(r[1][0], r[1][1], r[1][2], r[1][3]);             \
    P[slot][2] = pack4(r[2][0], r[2][1], r[2][2], r[2][3]);             \
    P[slot][3] = pack4(r[3][0], r[3][1], r[3][2], r[3][3]);             \
}

#define BODY(s0, s1, s2, hh) {                                          \
    int a0 = 0, a1 = 0;                                                 \
    _Pragma("unroll")                                                   \
    for (int n = 0; n < 3; ++n) {                                       \
        a0 = dot4(P[s0][n],     F[0][n], a0);                           \
        a1 = dot4(P[s0][n + 1], F[0][n], a1);                           \
        a0 = dot4(P[s1][n],     F[1][n], a0);                           \
        a1 = dot4(P[s1][n + 1], F[1][n], a1);                           \
        a0 = dot4(P[s2][n],     F[2][n], a0);                           \
        a1 = dot4(P[s2][n + 1], F[2][n], a1);                           \
    }                                                                   \
    a0 += __shfl_xor(a0, 1); a0 += __shfl_xor(a0, 2); a0 += __shfl_xor(a0, 4); \
    a1 += __shfl_xor(a1, 1); a1 += __shfl_xor(a1, 2); a1 += __shfl_xor(a1, 4); \
    if (ci == 0) {                                                      \
        long long v0 = (((long long)(a0 + bi)) * rm + rnd) >> ts;       \
        long long v1 = (((long long)(a1 + bi)) * rm + rnd) >> ts;       \
        int i0 = (int)v0 + zp, i1 = (int)v1 + zp;                       \
        i0 = min(127, max(-128, i0));                                   \
        i1 = min(127, max(-128, i1));                                   \
        int2v o_; o_[0] = i0; o_[1] = i1;                               \
        *reinterpret_cast<int2v*>(ob + (hh) * W_OUT_) = o_;             \
    }                                                                   \
}

#define STEP(sp, s0, s1, s2, hh, nr)  PACK(sp) LOADRAW(nr) BODY(s0, s1, s2, hh)

__global__ __launch_bounds__(256, 4) void conv2d_requant_kernel(
    const int* __restrict__ in,    // (64,226,226,32)
    const int* __restrict__ filt,  // (64,3,3,32)
    const int* __restrict__ bias,  // (64,)
    const int* __restrict__ qm_p,
    const int* __restrict__ ex_p,
    const int* __restrict__ zp_p,
    int* __restrict__ out)         // (64,224,224,1) int8 stored as int32
{
    const int bx   = blockIdx.x;           // 0..1791
    const int b    = bx / 28;
    const int seg  = bx % 28;
    const int widx = seg * 4 + (threadIdx.x >> 6);  // 0..111 per batch
    const int strip = widx / 14;           // 0..7  -> h0 = strip*28
    const int wseg  = widx % 14;           // 0..13 -> w0 = wseg*16
    const int h0 = strip * HB;
    const int w0 = wseg * 16;
    const int lane = threadIdx.x & 63;
    const int wi = lane >> 3;              // 0..7 : pair of output columns
    const int ci = lane & 7;               // 0..7 : channel chunk (4 ints)

    const int qm = qm_p[0];
    const int ex = ex_p[0];
    const int zp = zp_p[0];
    const int rm = (qm < 2147418112) ? ((qm + (1 << 15)) >> 16) : 32767;
    const int ts = 15 - ex;
    const long long rnd = 1LL << (ts - 1);
    const int bi = bias[b];

    // Packed per-lane filter fragment: 3x3, 4 channels/dword
    int F[3][3];
    {
        const int* fb = filt + b * 288 + ci * 4;
#pragma unroll
        for (int m = 0; m < 3; ++m) {
#pragma unroll
            for (int n = 0; n < 3; ++n) {
                int4v t = *(const int4v*)(fb + (m * 3 + n) * CIN_);
                F[m][n] = pack4(t[0], t[1], t[2], t[3]);
            }
        }
    }

    const int* base = in + b * IMGP + h0 * ROWP + (w0 + 2 * wi) * CIN_ + ci * 4;
    int* ob = out + (b * H_OUT_ + h0) * W_OUT_ + w0 + 2 * wi;

    // 4 packed window slots + 1 raw staging buffer
    int P[4][4];
    int4v r[4];
    LOADRAW(0) PACK(0)
    LOADRAW(1) PACK(1)
    LOADRAW(2) PACK(2)
    LOADRAW(3)

    for (int hh = 0; hh < HB; hh += 4) {
        STEP(3, 0, 1, 2, hh,     hh + 4)
        STEP(0, 1, 2, 3, hh + 1, hh + 5)
        STEP(1, 2, 3, 0, hh + 2, hh + 6)
        STEP(2, 3, 0, 1, hh + 3, hh + 7)
    }
}

extern "C" void kernel_launch(void* const* d_in, const int* in_sizes, int n_in,
                              void* d_out, int out_size, void* d_ws, size_t ws_size,
                              hipStream_t stream) {
    const int* in   = (const int*)d_in[0];
    const int* filt = (const int*)d_in[1];
    const int* bias = (const int*)d_in[2];
    const int* qm   = (const int*)d_in[3];
    const int* ex   = (const int*)d_in[4];
    const int* zp   = (const int*)d_in[5];
    int* out = (int*)d_out;

    dim3 grid(B_ * 28);   // 64 batches x 28 blocks (8 strips x 14 wsegs)
    dim3 block(256);
    hipLaunchKernelGGL(conv2d_requant_kernel, grid, block, 0, stream,
                       in, filt, bias, qm, ex, zp, out);
}